// Round 1
// 115.966 us; speedup vs baseline: 1.0532x; 1.0532x over previous
//
#include <hip/hip_runtime.h>
#include <hip/hip_bf16.h>

// DCNv2: B=4, C=64, H=W=128, O=64, KS=3, N=9, PAD=1. I/O float32.
#define BB 4
#define CC 64
#define HH 128
#define WW 128
#define OO 64
#define NN 9
#define HW 16384
#define HP 130
#define WP 130

// ---- ws layout (float-slot offsets) ----
#define WPMB_F  0
#define BPM_OFF 9216
#define WCB_F   9248
#define XT_F    27680
#define PX_OFF  2124832
#define PSZ     589824

typedef __attribute__((ext_vector_type(8))) short s8v;
typedef __attribute__((ext_vector_type(8))) unsigned short u8v;
typedef __attribute__((ext_vector_type(4))) float f4v;

__device__ __forceinline__ unsigned short f2bu(float f) {   // fp32 -> bf16 bits (RNE)
    unsigned int b = __float_as_uint(f);
    return (unsigned short)((b + 0x7FFFu + ((b >> 16) & 1u)) >> 16);
}
__device__ __forceinline__ float bu2f(unsigned short u) {
    return __uint_as_float(((unsigned int)u) << 16);
}

// Fused: blocks [0,1024) = NCHW fp32 -> NHWC bf16 transpose; blocks [1024,1248) = weight prep.
__global__ void __launch_bounds__(256) k_pxt(const float* __restrict__ x,
                                             const float* __restrict__ wp,
                                             const float* __restrict__ bp,
                                             const float* __restrict__ wm,
                                             const float* __restrict__ bm,
                                             const float* __restrict__ wcv,
                                             float* __restrict__ ws) {
    __shared__ unsigned short tile[64][66];
    int blk = blockIdx.x;
    int t = threadIdx.x;
    if (blk >= 1024) {                       // ---- weight prep path ----
        int tid = (blk - 1024) * 256 + t;
        if (tid < 18432) {                   // wpmb [32][576]
            int r = tid / 576;
            int kk = tid % 576;              // kk = kt*64 + c
            int kt = kk >> 6;
            int c = kk & 63;
            int dy = kt / 3, dx = kt % 3;
            float v = 0.f;
            if (r < 18)       v = wp[((r * 64 + c) * 3 + dy) * 3 + dx];
            else if (r < 27)  v = wm[(((r - 18) * 64 + c) * 3 + dy) * 3 + dx];
            ((unsigned short*)(ws + WPMB_F))[tid] = f2bu(v);
        } else if (tid < 18459) {
            int i = tid - 18432;
            ws[BPM_OFF + i] = (i < 18) ? bp[i] : bm[i - 18];
        } else if (tid >= 20480) {           // wcb [64][576], tid < 57344 by grid
            int d = tid - 20480;
            int o = d / 576;
            int kk = d % 576;
            int kt = kk >> 6;
            int c = kk & 63;
            ((unsigned short*)(ws + WCB_F))[o * 576 + kk] = f2bu(wcv[(o * 64 + c) * 9 + kt]);
        }
        return;
    }
    // ---- transpose path ----
    int b = blk >> 8;
    int hw0 = (blk & 255) * 64;
    unsigned short* xt = (unsigned short*)(ws + XT_F);
#pragma unroll
    for (int p = 0; p < 16; p++) {
        int c = p * 4 + (t >> 6);
        int i = t & 63;
        tile[c][i] = f2bu(x[((size_t)(b * 64 + c)) * HW + hw0 + i]);
    }
    __syncthreads();
#pragma unroll
    for (int p = 0; p < 16; p++) {
        int i = p * 4 + (t >> 6);
        int c = t & 63;
        xt[((size_t)(b * HW + hw0 + i)) * 64 + c] = tile[c][i];
    }
}

// Offset/modulation conv as MFMA GEMM: M=32(27), N=64 pixels/block, K=576.
// v2: double-buffered LDS, 1 barrier/kt, kt+1 loads issued before kt's MFMA.
__global__ void __launch_bounds__(256) k_off(const float* __restrict__ ws,
                                             float* __restrict__ wsout) {
    __shared__ unsigned short Awld[2][32 * 72];
    __shared__ unsigned short Bld[2][64 * 72];

    int t = threadIdx.x;
    int lane = t & 63;
    int wid = t >> 6;
    int ln15 = lane & 15;
    int quad = lane >> 4;

    int blk = blockIdx.x;          // 1024: 4 b * 256 tiles
    int b = blk >> 8;
    int hw0 = (blk & 255) * 64;

    const unsigned short* wpmb = (const unsigned short*)(ws + WPMB_F);
    const unsigned short* xtb = (const unsigned short*)(ws + XT_F) + (size_t)b * HW * 64;
    const float* bpm = ws + BPM_OFF;

    int aq_row = t >> 3, aq_g = t & 7;         // A: 32 rows x 8 groups
    int bq_pix = t & 63, bq_half = t >> 6;     // B: 64 pix x 4 ch-groups of 16
    int ph = (hw0 + bq_pix) >> 7;
    int pw = (hw0 + bq_pix) & 127;

    f4v acc[2];
    acc[0] = (f4v){0.f, 0.f, 0.f, 0.f};
    acc[1] = (f4v){0.f, 0.f, 0.f, 0.f};

    const u8v z = (u8v){0, 0, 0, 0, 0, 0, 0, 0};

    // ---- prologue: stage kt=0 into buffer 0 ----
    {
        u8v av = *(const u8v*)(wpmb + aq_row * 576 + aq_g * 8);
        int h2 = ph - 1, w2 = pw - 1;            // kt=0: dy=0, dx=0
        bool val = ((unsigned)h2 < 128u) && ((unsigned)w2 < 128u);
        u8v e0 = z, e1 = z;
        if (val) {
            const unsigned short* src = xtb + ((size_t)(h2 * 128 + w2)) * 64 + bq_half * 16;
            e0 = *(const u8v*)(src);
            e1 = *(const u8v*)(src + 8);
        }
        *(u8v*)(&Awld[0][aq_row * 72 + aq_g * 8]) = av;
        *(u8v*)(&Bld[0][bq_pix * 72 + bq_half * 16]) = e0;
        *(u8v*)(&Bld[0][bq_pix * 72 + bq_half * 16 + 8]) = e1;
    }
    __syncthreads();

#pragma unroll 1
    for (int kt = 0; kt < 9; kt++) {
        int cur = kt & 1, nxt = cur ^ 1;
        u8v an = z, n0 = z, n1 = z;
        if (kt < 8) {                            // issue kt+1 loads BEFORE MFMA
            int k2 = kt + 1;
            an = *(const u8v*)(wpmb + aq_row * 576 + k2 * 64 + aq_g * 8);
            int dy = k2 / 3, dx = k2 % 3;
            int h2 = ph + dy - 1, w2 = pw + dx - 1;
            bool val = ((unsigned)h2 < 128u) && ((unsigned)w2 < 128u);
            if (val) {
                const unsigned short* src = xtb + ((size_t)(h2 * 128 + w2)) * 64 + bq_half * 16;
                n0 = *(const u8v*)(src);
                n1 = *(const u8v*)(src + 8);
            }
        }
#pragma unroll
        for (int ks = 0; ks < 2; ks++) {
            s8v bf = *(const s8v*)(&Bld[cur][(wid * 16 + ln15) * 72 + ks * 32 + quad * 8]);
#pragma unroll
            for (int mt = 0; mt < 2; mt++) {
                s8v af = *(const s8v*)(&Awld[cur][(mt * 16 + ln15) * 72 + ks * 32 + quad * 8]);
                acc[mt] = __builtin_amdgcn_mfma_f32_16x16x32_bf16(af, bf, acc[mt], 0, 0, 0);
            }
        }
        if (kt < 8) {                            // write into the other buffer
            *(u8v*)(&Awld[nxt][aq_row * 72 + aq_g * 8]) = an;
            *(u8v*)(&Bld[nxt][bq_pix * 72 + bq_half * 16]) = n0;
            *(u8v*)(&Bld[nxt][bq_pix * 72 + bq_half * 16 + 8]) = n1;
        }
        __syncthreads();
    }

    // epilogue: D col = pixel (wid*16+ln15), row = oc (mt*16 + quad*4 + r)
    int p = hw0 + wid * 16 + ln15;
    int h = p >> 7, w = p & 127;
    float* pxA = wsout + PX_OFF;
    float* pyA = pxA + PSZ;
    float* mmA = pyA + PSZ;
#pragma unroll
    for (int mt = 0; mt < 2; mt++) {
#pragma unroll
        for (int r = 0; r < 4; r++) {
            int oc = mt * 16 + quad * 4 + r;
            if (oc < 27) {
                float v = acc[mt][r] + bpm[oc];
                if (oc < 9) {
                    int ki = oc / 3;
                    pxA[((size_t)b * NN + oc) * HW + p] = v + (float)(ki - 1) + (float)(h + 1);
                } else if (oc < 18) {
                    int k = oc - 9;
                    int kj = k % 3;
                    pyA[((size_t)b * NN + k) * HW + p] = v + (float)(kj - 1) + (float)(w + 1);
                } else {
                    int k = oc - 18;
                    mmA[((size_t)b * NN + k) * HW + p] = 1.f / (1.f + __expf(-v));
                }
            }
        }
    }
}

// Fused sampler + MFMA einsum. 64 pixels x 64 oc per block, K=576, chunk=64/tap.
// v2: double-buffered LDS, 1 barrier/kt, gathers+A for kt+1 issued before kt's MFMA,
// px/py/m prefetched 2 taps ahead, blend after MFMA.
__global__ void __launch_bounds__(256) k_gemm(const float* __restrict__ ws,
                                              float* __restrict__ out) {
    __shared__ unsigned short Ald[2][64 * 72];   // Wc [o][k] stride 72
    __shared__ unsigned short Sld[2][64 * 72];   // S  [pix][k] stride 72

    int t = threadIdx.x;
    int lane = t & 63;
    int wid = t >> 6;
    int ln15 = lane & 15;
    int quad = lane >> 4;

    int blk = blockIdx.x;            // 1024: 4 b * 256 tiles
    int b = blk >> 8;
    int hw0 = (blk & 255) * 64;

    const unsigned short* wcb = (const unsigned short*)(ws + WCB_F);
    const unsigned short* xtb = (const unsigned short*)(ws + XT_F) + (size_t)b * HW * 64;
    const float* pxA = ws + PX_OFF;
    const float* pyA = pxA + PSZ;
    const float* mmA = pyA + PSZ;

    int p_loc = t >> 2;              // pixel within tile (sampling role)
    int cq = t & 3;                  // 16-channel group
    int cbase = cq * 16;
    int arow = t >> 2, ag = t & 3;   // A staging roles

    f4v acc[4];
#pragma unroll
    for (int mt = 0; mt < 4; mt++) acc[mt] = (f4v){0.f, 0.f, 0.f, 0.f};

    size_t pbase = (size_t)b * NN * HW + (size_t)(hw0 + p_loc);

    auto desc = [&](float px, float py, float mk,
                    float& g0, float& g1, float& g2, float& g3,
                    int& o0, int& o1, int& o2, int& o3) {
        float fx = floorf(px), fy = floorf(py);
        float pxc = fminf(fmaxf(px, 0.f), (float)(HP - 1));
        float pyc = fminf(fmaxf(py, 0.f), (float)(WP - 1));
        int qltx = (int)fminf(fmaxf(fx, 0.f), (float)(HP - 1));
        int qlty = (int)fminf(fmaxf(fy, 0.f), (float)(WP - 1));
        int qrbx = (int)fminf(fmaxf(fx + 1.f, 0.f), (float)(HP - 1));
        int qrby = (int)fminf(fmaxf(fy + 1.f, 0.f), (float)(WP - 1));

        float gltx = 1.f + ((float)qltx - pxc);
        float glty = 1.f + ((float)qlty - pyc);
        float grbx = 1.f - ((float)qrbx - pxc);
        float grby = 1.f - ((float)qrby - pyc);

        bool vlx = (qltx >= 1) && (qltx <= HH);
        bool vly = (qlty >= 1) && (qlty <= WW);
        bool vrx = (qrbx >= 1) && (qrbx <= HH);
        bool vry = (qrby >= 1) && (qrby <= WW);
        g0 = (vlx && vly) ? gltx * glty * mk : 0.f;
        g1 = (vrx && vry) ? grbx * grby * mk : 0.f;
        g2 = (vlx && vry) ? gltx * grby * mk : 0.f;
        g3 = (vrx && vly) ? grbx * glty * mk : 0.f;

        int xlt = min(max(qltx - 1, 0), HH - 1);
        int ylt = min(max(qlty - 1, 0), WW - 1);
        int xrb = min(max(qrbx - 1, 0), HH - 1);
        int yrb = min(max(qrby - 1, 0), WW - 1);
        o0 = (xlt * WW + ylt) * 64 + cbase;
        o1 = (xrb * WW + yrb) * 64 + cbase;
        o2 = (xlt * WW + yrb) * 64 + cbase;
        o3 = (xrb * WW + ylt) * 64 + cbase;
    };

    // ---- prologue: sample kt=0 into buffer 0; prefetch kt=1 descriptors ----
    float pxn, pyn, mkn;
    {
        float px = pxA[pbase], py = pyA[pbase], mk = mmA[pbase];
        pxn = pxA[pbase + HW]; pyn = pyA[pbase + HW]; mkn = mmA[pbase + HW];
        float g0, g1, g2, g3; int o0, o1, o2, o3;
        desc(px, py, mk, g0, g1, g2, g3, o0, o1, o2, o3);
        u8v e0a = *(const u8v*)(xtb + o0), e0b = *(const u8v*)(xtb + o0 + 8);
        u8v e1a = *(const u8v*)(xtb + o1), e1b = *(const u8v*)(xtb + o1 + 8);
        u8v e2a = *(const u8v*)(xtb + o2), e2b = *(const u8v*)(xtb + o2 + 8);
        u8v e3a = *(const u8v*)(xtb + o3), e3b = *(const u8v*)(xtb + o3 + 8);
        u8v a0 = *(const u8v*)(wcb + arow * 576 + ag * 16);
        u8v a1 = *(const u8v*)(wcb + arow * 576 + ag * 16 + 8);
        u8v sva, svb;
#pragma unroll
        for (int j = 0; j < 8; j++) {
            float va = g0 * bu2f(e0a[j]) + g1 * bu2f(e1a[j])
                     + g2 * bu2f(e2a[j]) + g3 * bu2f(e3a[j]);
            float vb = g0 * bu2f(e0b[j]) + g1 * bu2f(e1b[j])
                     + g2 * bu2f(e2b[j]) + g3 * bu2f(e3b[j]);
            sva[j] = f2bu(va);
            svb[j] = f2bu(vb);
        }
        *(u8v*)(&Sld[0][p_loc * 72 + cbase]) = sva;
        *(u8v*)(&Sld[0][p_loc * 72 + cbase + 8]) = svb;
        *(u8v*)(&Ald[0][arow * 72 + ag * 16]) = a0;
        *(u8v*)(&Ald[0][arow * 72 + ag * 16 + 8]) = a1;
    }
    __syncthreads();

#pragma unroll 1
    for (int kt = 0; kt < 9; kt++) {
        int cur = kt & 1, nxt = cur ^ 1;
        float g0 = 0.f, g1 = 0.f, g2 = 0.f, g3 = 0.f;
        u8v e0a, e0b, e1a, e1b, e2a, e2b, e3a, e3b, a0, a1;
        if (kt < 8) {                        // issue kt+1 loads BEFORE MFMA phase
            int o0, o1, o2, o3;
            desc(pxn, pyn, mkn, g0, g1, g2, g3, o0, o1, o2, o3);
            e0a = *(const u8v*)(xtb + o0); e0b = *(const u8v*)(xtb + o0 + 8);
            e1a = *(const u8v*)(xtb + o1); e1b = *(const u8v*)(xtb + o1 + 8);
            e2a = *(const u8v*)(xtb + o2); e2b = *(const u8v*)(xtb + o2 + 8);
            e3a = *(const u8v*)(xtb + o3); e3b = *(const u8v*)(xtb + o3 + 8);
            a0 = *(const u8v*)(wcb + arow * 576 + (kt + 1) * 64 + ag * 16);
            a1 = *(const u8v*)(wcb + arow * 576 + (kt + 1) * 64 + ag * 16 + 8);
            if (kt < 7) {                    // prefetch descriptors 2 taps ahead
                size_t pn = pbase + (size_t)(kt + 2) * HW;
                pxn = pxA[pn]; pyn = pyA[pn]; mkn = mmA[pn];
            }
        }
#pragma unroll
        for (int ks = 0; ks < 2; ks++) {
            s8v bf = *(const s8v*)(&Sld[cur][(wid * 16 + ln15) * 72 + ks * 32 + quad * 8]);
#pragma unroll
            for (int mt = 0; mt < 4; mt++) {
                s8v af = *(const s8v*)(&Ald[cur][(mt * 16 + ln15) * 72 + ks * 32 + quad * 8]);
                acc[mt] = __builtin_amdgcn_mfma_f32_16x16x32_bf16(af, bf, acc[mt], 0, 0, 0);
            }
        }
        if (kt < 8) {                        // blend after MFMA, write other buffer
            u8v sva, svb;
#pragma unroll
            for (int j = 0; j < 8; j++) {
                float va = g0 * bu2f(e0a[j]) + g1 * bu2f(e1a[j])
                         + g2 * bu2f(e2a[j]) + g3 * bu2f(e3a[j]);
                float vb = g0 * bu2f(e0b[j]) + g1 * bu2f(e1b[j])
                         + g2 * bu2f(e2b[j]) + g3 * bu2f(e3b[j]);
                sva[j] = f2bu(va);
                svb[j] = f2bu(vb);
            }
            *(u8v*)(&Sld[nxt][p_loc * 72 + cbase]) = sva;
            *(u8v*)(&Sld[nxt][p_loc * 72 + cbase + 8]) = svb;
            *(u8v*)(&Ald[nxt][arow * 72 + ag * 16]) = a0;
            *(u8v*)(&Ald[nxt][arow * 72 + ag * 16 + 8]) = a1;
        }
        __syncthreads();
    }

    // epilogue: D col = pixel, row = oc
    int pix = hw0 + wid * 16 + ln15;
    float* ob = out + (size_t)b * (OO * HW) + pix;
#pragma unroll
    for (int mt = 0; mt < 4; mt++) {
#pragma unroll
        for (int r = 0; r < 4; r++) {
            ob[(size_t)(mt * 16 + quad * 4 + r) * HW] = acc[mt][r];
        }
    }
}

extern "C" void kernel_launch(void* const* d_in, const int* in_sizes, int n_in,
                              void* d_out, int out_size, void* d_ws, size_t ws_size,
                              hipStream_t stream) {
    const float* x   = (const float*)d_in[0];
    const float* wp  = (const float*)d_in[1];
    const float* bp  = (const float*)d_in[2];
    const float* wm  = (const float*)d_in[3];
    const float* bm  = (const float*)d_in[4];
    const float* wcv = (const float*)d_in[5];
    float* ws = (float*)d_ws;
    float* out = (float*)d_out;

    hipLaunchKernelGGL(k_pxt, dim3(1248), dim3(256), 0, stream, x, wp, bp, wm, bm, wcv, ws);
    hipLaunchKernelGGL(k_off, dim3(1024), dim3(256), 0, stream, ws, ws);
    hipLaunchKernelGGL(k_gemm, dim3(1024), dim3(256), 0, stream, ws, out);
}